// Round 1
// baseline (21910.046 us; speedup 1.0000x reference)
//
#include <hip/hip_runtime.h>
#include <math.h>

#define NN 325
#define BB 128
#define TT 12
#define HH 128
#define DFD 32
#define ODD 2
#define AUXD 2
#define MROWS (NN*BB)      // 41600
#define G3 (3*HH)          // 384
#define COLS (BB*HH)       // 16384

__device__ __forceinline__ float sigmoidf_(float x) { return 1.0f / (1.0f + expf(-x)); }

// ---------------------------------------------------------------------------
// GRU: computes h = z*h + (1-z)*c for 16 rows per block.
// LAYER 0: x = [data(4) | feat(32)], data from d_out[t-1] + label aux[t-1]
// LAYER 1: x = [d(128) | feat(32)]
// block = 384 threads; thread (jg=tid%96, rg=tid/96) owns 4 j-cols x 4 rows.
// ---------------------------------------------------------------------------
template<int KX, int LAYER>
__global__ __launch_bounds__(384) void gru_kernel(
    const float* __restrict__ xin,
    const float* __restrict__ outbuf,
    const float* __restrict__ label,
    const float* __restrict__ feat,
    float* __restrict__ h,
    const float* __restrict__ Wx,
    const float* __restrict__ Wh,
    const float* __restrict__ bias,
    int t)
{
    constexpr int ROWS = 16;
    __shared__ float xs[KX][ROWS];
    __shared__ float hs[HH][ROWS];
    __shared__ float ep_z[ROWS][HH];
    __shared__ float ep_r[ROWS][HH];
    __shared__ float ep_gc[ROWS][HH];
    __shared__ float ep_hc[ROWS][HH];

    const int row0 = blockIdx.x * ROWS;
    const int tid  = threadIdx.x;

    // stage x (transposed [k][r])
    for (int idx = tid; idx < KX * ROWS; idx += 384) {
        const int r = idx & (ROWS - 1);
        const int k = idx / ROWS;
        const int row = row0 + r;
        float v;
        if constexpr (LAYER == 0) {
            if (k < 4) {
                if (t == 0) {
                    v = 0.0f;
                } else if (k < ODD) {
                    v = outbuf[(size_t)(row * TT + (t - 1)) * ODD + k];
                } else {
                    v = label[(size_t)(row * TT + (t - 1)) * (ODD + AUXD) + ODD + (k - ODD)];
                }
            } else {
                v = feat[(row >> 7) * DFD + (k - 4)];
            }
        } else {
            if (k < HH) v = xin[(size_t)row * HH + k];
            else        v = feat[(row >> 7) * DFD + (k - HH)];
        }
        xs[k][r] = v;
    }
    // stage h (transposed [k][r])
    for (int idx = tid; idx < HH * ROWS; idx += 384) {
        const int r = idx & (ROWS - 1);
        const int k = idx / ROWS;
        hs[k][r] = h[(size_t)(row0 + r) * HH + k];
    }
    __syncthreads();

    const int jg = tid % 96;
    const int rg = tid / 96;
    const int j0 = jg * 4, r0 = rg * 4;

    float accg[4][4] = {};
    float acch[4][4] = {};

    for (int k = 0; k < KX; ++k) {
        const float4 xv = *(const float4*)&xs[k][r0];
        const float4 wv = *(const float4*)&Wx[k * G3 + j0];
        const float xa[4] = {xv.x, xv.y, xv.z, xv.w};
        const float wa[4] = {wv.x, wv.y, wv.z, wv.w};
        #pragma unroll
        for (int p = 0; p < 4; ++p)
            #pragma unroll
            for (int q = 0; q < 4; ++q)
                accg[p][q] = fmaf(xa[p], wa[q], accg[p][q]);
    }
    for (int k = 0; k < HH; ++k) {
        const float4 xv = *(const float4*)&hs[k][r0];
        const float4 wv = *(const float4*)&Wh[k * G3 + j0];
        const float xa[4] = {xv.x, xv.y, xv.z, xv.w};
        const float wa[4] = {wv.x, wv.y, wv.z, wv.w};
        #pragma unroll
        for (int p = 0; p < 4; ++p)
            #pragma unroll
            for (int q = 0; q < 4; ++q)
                acch[p][q] = fmaf(xa[p], wa[q], acch[p][q]);
    }

    #pragma unroll
    for (int q = 0; q < 4; ++q) {
        const int j = j0 + q;
        const float bj = bias[j];
        #pragma unroll
        for (int p = 0; p < 4; ++p) {
            const int r = r0 + p;
            const float g = accg[p][q] + bj;
            const float s = g + acch[p][q];
            if (j < HH)            ep_z[r][j] = sigmoidf_(s);
            else if (j < 2 * HH)   ep_r[r][j - HH] = sigmoidf_(s);
            else { ep_gc[r][j - 2 * HH] = g; ep_hc[r][j - 2 * HH] = acch[p][q]; }
        }
    }
    __syncthreads();

    for (int idx = tid; idx < ROWS * HH; idx += 384) {
        const int r = idx >> 7;
        const int j = idx & (HH - 1);
        const float z  = ep_z[r][j];
        const float rr = ep_r[r][j];
        const float c  = tanhf(ep_gc[r][j] + rr * ep_hc[r][j]);
        const float hold = hs[j][r];
        h[(size_t)(row0 + r) * HH + j] = z * hold + (1.0f - z) * c;
    }
}

// ---------------------------------------------------------------------------
// Node mixing: O1[n,col] = sum_m A1[n,m] X[m,col]; O2 likewise (shared X read).
// A reads are wave-uniform -> scalar loads; X reads coalesced.
// ---------------------------------------------------------------------------
__global__ __launch_bounds__(256) void spmm_kernel(
    const float* __restrict__ X,
    const float* __restrict__ A1,
    const float* __restrict__ A2,
    float* __restrict__ O1,
    float* __restrict__ O2)
{
    constexpr int NT = 16;
    const int n0  = blockIdx.x * NT;
    const int col = blockIdx.y * 256 + threadIdx.x;
    float acc1[NT] = {};
    float acc2[NT] = {};
    #pragma unroll 5
    for (int m = 0; m < NN; ++m) {
        const float xv = X[(size_t)m * COLS + col];
        #pragma unroll
        for (int i = 0; i < NT; ++i) {
            const int n = (n0 + i < NN) ? (n0 + i) : (NN - 1);
            acc1[i] = fmaf(A1[n * NN + m], xv, acc1[i]);
            acc2[i] = fmaf(A2[n * NN + m], xv, acc2[i]);
        }
    }
    #pragma unroll
    for (int i = 0; i < NT; ++i) {
        const int n = n0 + i;
        if (n < NN) {
            O1[(size_t)n * COLS + col] = acc1[i];
            O2[(size_t)n * COLS + col] = acc2[i];
        }
    }
}

// ---------------------------------------------------------------------------
// Channel mixing: D[row,j] = 0.5*(T1[row,:]@W1[:,j] + T2[row,:]@W2[:,j]).
// D may alias T1 (rows staged into LDS before stores). block=256, 32 rows.
// ---------------------------------------------------------------------------
__global__ __launch_bounds__(256) void gcmix_kernel(
    const float* T1, const float* T2,
    const float* __restrict__ W1, const float* __restrict__ W2,
    float* D)
{
    constexpr int ROWS = 32;
    __shared__ float t1s[HH][ROWS];
    __shared__ float t2s[HH][ROWS];
    const int row0 = blockIdx.x * ROWS;
    const int tid  = threadIdx.x;

    for (int idx = tid; idx < ROWS * HH; idx += 256) {
        const int r = idx & (ROWS - 1);
        const int k = idx / ROWS;
        t1s[k][r] = T1[(size_t)(row0 + r) * HH + k];
        t2s[k][r] = T2[(size_t)(row0 + r) * HH + k];
    }
    __syncthreads();

    const int jg = tid & 31;
    const int rg = tid >> 5;
    const int j0 = jg * 4, r0 = rg * 4;

    float acc[4][4] = {};
    for (int k = 0; k < HH; ++k) {
        const float4 x1 = *(const float4*)&t1s[k][r0];
        const float4 x2 = *(const float4*)&t2s[k][r0];
        const float4 w1 = *(const float4*)&W1[k * HH + j0];
        const float4 w2 = *(const float4*)&W2[k * HH + j0];
        const float x1a[4] = {x1.x, x1.y, x1.z, x1.w};
        const float x2a[4] = {x2.x, x2.y, x2.z, x2.w};
        const float w1a[4] = {w1.x, w1.y, w1.z, w1.w};
        const float w2a[4] = {w2.x, w2.y, w2.z, w2.w};
        #pragma unroll
        for (int p = 0; p < 4; ++p)
            #pragma unroll
            for (int q = 0; q < 4; ++q)
                acc[p][q] = fmaf(x1a[p], w1a[q], fmaf(x2a[p], w2a[q], acc[p][q]));
    }

    #pragma unroll
    for (int p = 0; p < 4; ++p)
        #pragma unroll
        for (int q = 0; q < 4; ++q)
            D[(size_t)(row0 + r0 + p) * HH + (j0 + q)] = 0.5f * acc[p][q];
}

// ---------------------------------------------------------------------------
// Projection: out[row,t,c] = [d | feat] @ Wp + bp  (c = 0..1)
// ---------------------------------------------------------------------------
__global__ __launch_bounds__(256) void proj_kernel(
    const float* __restrict__ d,
    const float* __restrict__ feat,
    const float* __restrict__ Wp,
    const float* __restrict__ bp,
    float* __restrict__ out,
    int t)
{
    const int row = blockIdx.x * 256 + threadIdx.x;
    if (row >= MROWS) return;
    const int n = row >> 7;
    float a0 = bp[0], a1 = bp[1];
    for (int k = 0; k < HH; ++k) {
        const float v = d[(size_t)row * HH + k];
        a0 = fmaf(v, Wp[k * ODD + 0], a0);
        a1 = fmaf(v, Wp[k * ODD + 1], a1);
    }
    for (int k = 0; k < DFD; ++k) {
        const float v = feat[n * DFD + k];
        a0 = fmaf(v, Wp[(HH + k) * ODD + 0], a0);
        a1 = fmaf(v, Wp[(HH + k) * ODD + 1], a1);
    }
    out[(size_t)(row * TT + t) * ODD + 0] = a0;
    out[(size_t)(row * TT + t) * ODD + 1] = a1;
}

extern "C" void kernel_launch(void* const* d_in, const int* in_sizes, int n_in,
                              void* d_out, int out_size, void* d_ws, size_t ws_size,
                              hipStream_t stream)
{
    const float* feature = (const float*)d_in[0];
    const float* label   = (const float*)d_in[1];
    const float* state0  = (const float*)d_in[2];
    const float* state1  = (const float*)d_in[3];
    const float* Wx0 = (const float*)d_in[4];
    const float* Wh0 = (const float*)d_in[5];
    const float* b0  = (const float*)d_in[6];
    const float* Wx1 = (const float*)d_in[7];
    const float* Wh1 = (const float*)d_in[8];
    const float* b1  = (const float*)d_in[9];
    const float* A01 = (const float*)d_in[10];
    const float* A02 = (const float*)d_in[11];
    const float* Wg01 = (const float*)d_in[12];
    const float* Wg02 = (const float*)d_in[13];
    const float* A11 = (const float*)d_in[14];
    const float* A12 = (const float*)d_in[15];
    const float* Wg11 = (const float*)d_in[16];
    const float* Wg12 = (const float*)d_in[17];
    const float* Wp  = (const float*)d_in[18];
    const float* bp  = (const float*)d_in[19];

    float* out = (float*)d_out;
    float* ws  = (float*)d_ws;
    const size_t S = (size_t)MROWS * HH;
    float* h0 = ws;
    float* h1 = ws + S;
    float* t1 = ws + 2 * S;   // also serves as the "d" buffer
    float* t2 = ws + 3 * S;

    hipMemcpyAsync(h0, state0, S * sizeof(float), hipMemcpyDeviceToDevice, stream);
    hipMemcpyAsync(h1, state1, S * sizeof(float), hipMemcpyDeviceToDevice, stream);

    const dim3 spmmGrid((NN + 15) / 16, COLS / 256);

    for (int t = 0; t < TT; ++t) {
        gru_kernel<ODD + AUXD + DFD, 0><<<MROWS / 16, 384, 0, stream>>>(
            nullptr, out, label, feature, h0, Wx0, Wh0, b0, t);
        spmm_kernel<<<spmmGrid, 256, 0, stream>>>(h0, A01, A02, t1, t2);
        gcmix_kernel<<<MROWS / 32, 256, 0, stream>>>(t1, t2, Wg01, Wg02, t1);
        gru_kernel<HH + DFD, 1><<<MROWS / 16, 384, 0, stream>>>(
            t1, nullptr, label, feature, h1, Wx1, Wh1, b1, t);
        spmm_kernel<<<spmmGrid, 256, 0, stream>>>(h1, A11, A12, t1, t2);
        gcmix_kernel<<<MROWS / 32, 256, 0, stream>>>(t1, t2, Wg11, Wg12, t1);
        proj_kernel<<<(MROWS + 255) / 256, 256, 0, stream>>>(t1, feature, Wp, bp, out, t);
    }
}

// Round 3
// 2490.928 us; speedup vs baseline: 8.7959x; 8.7959x over previous
//
#include <hip/hip_runtime.h>
#include <math.h>

#define NN 325
#define NPAD 336     // n padded for A rows (16-mult)
#define KPAD 352     // node dim padded for K loop (32-mult)
#define BBv 128
#define TTv 12
#define HHv 128
#define DFDv 32
#define ODDv 2
#define MROWS (NN*BBv)   // 41600
#define G3v 384

typedef __attribute__((ext_vector_type(8))) short bf16x8;
typedef __attribute__((ext_vector_type(4))) float f32x4;
typedef __attribute__((ext_vector_type(8))) unsigned short ushort8;
typedef unsigned short ushort;

__device__ __forceinline__ ushort f2bf(float f) {
    union { float f; unsigned u; } v; v.f = f;
    unsigned r = v.u + 0x7FFFu + ((v.u >> 16) & 1u);
    return (ushort)(r >> 16);
}
__device__ __forceinline__ float sigmoidf_(float x) { return 1.0f / (1.0f + __expf(-x)); }

#define MFMA(a,b,c) __builtin_amdgcn_mfma_f32_16x16x32_bf16((a),(b),(c),0,0,0)

// ---------------------------------------------------------------------------
// converters (run once per launch; ~1.5M elements total)
// ---------------------------------------------------------------------------
__global__ void wtrans_kernel(const float* __restrict__ W, ushort* __restrict__ Wt,
                              int K, int N, int KP) {
    int idx = blockIdx.x * 256 + threadIdx.x;
    if (idx >= N * KP) return;
    int n = idx / KP, k = idx - n * KP;
    Wt[idx] = f2bf(k < K ? W[(size_t)k * N + n] : 0.f);
}
__global__ void aconv_kernel(const float* __restrict__ A, ushort* __restrict__ Ab) {
    int idx = blockIdx.x * 256 + threadIdx.x;
    if (idx >= NPAD * KPAD) return;
    int n = idx / KPAD, m = idx - n * KPAD;
    Ab[idx] = f2bf((n < NN && m < NN) ? A[n * NN + m] : 0.f);
}
__global__ void fconv_kernel(const float* __restrict__ F, ushort* __restrict__ Fb) {
    int idx = blockIdx.x * 256 + threadIdx.x;
    if (idx >= NPAD * DFDv) return;
    int n = idx >> 5, c = idx & 31;
    Fb[idx] = f2bf(n < NN ? F[n * DFDv + c] : 0.f);
}

// ---------------------------------------------------------------------------
// GRU (MFMA). Block: 32 n's at fixed b, full 384 gate cols. 512 thr = 8 waves.
// Wave w owns cols {w*16, 128+w*16, 256+w*16} so z/r/c triples are lane-local.
// Writes h fp32 (state) and transposed bf16 xt[col=(b,ch)][node].
// ---------------------------------------------------------------------------
template<int KP, int LAYER>
__global__ __launch_bounds__(512) void gru_mfma(
    float* __restrict__ h,              // [41600][128] fp32 in/out
    const ushort* __restrict__ dsrc,    // L1: d bf16 [41600][128]
    const float* __restrict__ outbuf,   // L0: [41600][12][2]
    const float* __restrict__ label,    // L0: [41600][12][4]
    const ushort* __restrict__ featb,   // [336][32] bf16
    const ushort* __restrict__ Wxt,     // [384][KP] bf16
    const ushort* __restrict__ Wht,     // [384][128] bf16
    const float* __restrict__ bias,     // [384]
    ushort* __restrict__ xt,            // [16384][352] bf16 out (transposed h)
    int t)
{
    __shared__ ushort hs[32][136];
    __shared__ ushort xs[32][KP + 8];
    __shared__ ushort hnb[32][136];

    const int n0 = blockIdx.x * 32;
    const int b  = blockIdx.y;
    const int tid = threadIdx.x;

    // ---- stage h tile (bf16, K-fast) ----
    {
        int i = tid >> 4, c0 = (tid & 15) * 8;
        int n = n0 + i; if (n > NN - 1) n = NN - 1;
        const float* src = h + ((size_t)(n * BBv + b) * HHv + c0);
        float4 v0 = *(const float4*)src;
        float4 v1 = *(const float4*)(src + 4);
        ushort* dst = &hs[i][c0];
        dst[0]=f2bf(v0.x); dst[1]=f2bf(v0.y); dst[2]=f2bf(v0.z); dst[3]=f2bf(v0.w);
        dst[4]=f2bf(v1.x); dst[5]=f2bf(v1.y); dst[6]=f2bf(v1.z); dst[7]=f2bf(v1.w);
    }
    // ---- stage x tile ----
    if (LAYER == 0) {
        for (int e = tid; e < 32 * KP; e += 512) {
            int i = e / KP, k = e - i * KP;
            int n = n0 + i; if (n > NN - 1) n = NN - 1;
            size_t r = (size_t)n * BBv + b;
            ushort v;
            if (k < 2)       v = (t == 0) ? 0 : f2bf(outbuf[(r * TTv + (t - 1)) * ODDv + k]);
            else if (k < 4)  v = (t == 0) ? 0 : f2bf(label[(r * TTv + (t - 1)) * 4 + 2 + (k - 2)]);
            else if (k < 36) v = featb[n * DFDv + (k - 4)];
            else             v = 0;
            xs[i][k] = v;
        }
    } else {
        int i = tid >> 4, c0 = (tid & 15) * 8;
        int n = n0 + i; if (n > NN - 1) n = NN - 1;
        *(ushort8*)&xs[i][c0] = *(const ushort8*)(dsrc + ((size_t)(n * BBv + b) * HHv + c0));
        if (tid < 128) {
            int i2 = tid >> 2, c2 = (tid & 3) * 8;
            int n2 = n0 + i2; if (n2 > NN - 1) n2 = NN - 1;
            *(ushort8*)&xs[i2][HHv + c2] = *(const ushort8*)(featb + n2 * DFDv + c2);
        }
    }
    __syncthreads();

    const int w = tid >> 6, l = tid & 63;
    const int lr = l & 15, lk = l >> 4;
    const int jj0 = w * 16, jj1 = 128 + w * 16, jj2 = 256 + w * 16;

    f32x4 aG[3][2], aH[3][2];
    #pragma unroll
    for (int j = 0; j < 3; ++j)
        #pragma unroll
        for (int m = 0; m < 2; ++m) {
            aG[j][m] = (f32x4){0.f,0.f,0.f,0.f};
            aH[j][m] = (f32x4){0.f,0.f,0.f,0.f};
        }

    // x @ Wx
    #pragma unroll
    for (int kk = 0; kk < KP / 32; ++kk) {
        const int kb = kk * 32 + lk * 8;
        bf16x8 a0 = *(const bf16x8*)&xs[lr][kb];
        bf16x8 a1 = *(const bf16x8*)&xs[16 + lr][kb];
        bf16x8 b0 = *(const bf16x8*)(Wxt + (size_t)(jj0 + lr) * KP + kb);
        bf16x8 b1 = *(const bf16x8*)(Wxt + (size_t)(jj1 + lr) * KP + kb);
        bf16x8 b2 = *(const bf16x8*)(Wxt + (size_t)(jj2 + lr) * KP + kb);
        aG[0][0] = MFMA(a0, b0, aG[0][0]); aG[0][1] = MFMA(a1, b0, aG[0][1]);
        aG[1][0] = MFMA(a0, b1, aG[1][0]); aG[1][1] = MFMA(a1, b1, aG[1][1]);
        aG[2][0] = MFMA(a0, b2, aG[2][0]); aG[2][1] = MFMA(a1, b2, aG[2][1]);
    }
    // h @ Wh
    #pragma unroll
    for (int kk = 0; kk < 4; ++kk) {
        const int kb = kk * 32 + lk * 8;
        bf16x8 a0 = *(const bf16x8*)&hs[lr][kb];
        bf16x8 a1 = *(const bf16x8*)&hs[16 + lr][kb];
        bf16x8 b0 = *(const bf16x8*)(Wht + (size_t)(jj0 + lr) * HHv + kb);
        bf16x8 b1 = *(const bf16x8*)(Wht + (size_t)(jj1 + lr) * HHv + kb);
        bf16x8 b2 = *(const bf16x8*)(Wht + (size_t)(jj2 + lr) * HHv + kb);
        aH[0][0] = MFMA(a0, b0, aH[0][0]); aH[0][1] = MFMA(a1, b0, aH[0][1]);
        aH[1][0] = MFMA(a0, b1, aH[1][0]); aH[1][1] = MFMA(a1, b1, aH[1][1]);
        aH[2][0] = MFMA(a0, b2, aH[2][0]); aH[2][1] = MFMA(a1, b2, aH[2][1]);
    }

    // ---- in-register gating ----
    const int ch = w * 16 + lr;
    const float bz = bias[ch], br = bias[128 + ch], bc = bias[256 + ch];
    #pragma unroll
    for (int m = 0; m < 2; ++m) {
        #pragma unroll
        for (int i = 0; i < 4; ++i) {
            int row_local = m * 16 + lk * 4 + i;
            int n = n0 + row_local;
            int nc = (n > NN - 1) ? NN - 1 : n;
            size_t idx = ((size_t)(nc * BBv + b)) * HHv + ch;
            float z  = sigmoidf_(aG[0][m][i] + bz + aH[0][m][i]);
            float rr = sigmoidf_(aG[1][m][i] + br + aH[1][m][i]);
            float c  = tanhf(aG[2][m][i] + bc + rr * aH[2][m][i]);
            float hold = h[idx];
            float hn = z * hold + (1.f - z) * c;
            if (n < NN) h[idx] = hn;
            hnb[row_local][ch] = f2bf(hn);
        }
    }
    __syncthreads();

    // ---- transposed xt write: thread = (ch, n-chunk of 8) ----
    {
        int chx = tid >> 2, g = tid & 3;
        ushort8 v;
        #pragma unroll
        for (int k = 0; k < 8; ++k) v[k] = hnb[g * 8 + k][chx];
        *(ushort8*)(xt + (size_t)(b * HHv + chx) * KPAD + n0 + g * 8) = v;
    }
}

// ---------------------------------------------------------------------------
// Fused graph-conv: m1 = A1·X, m2 = A2·X (GEMM1, MFMA, operands from global),
// D = 0.5*(m1@W1 + m2@W2) (GEMM2, MFMA via LDS). L0: write d bf16. L1: proj.
// Block = 16 n's x 256 cols (2 b's), 256 thr = 4 waves.
// ---------------------------------------------------------------------------
template<int LAYER>
__global__ __launch_bounds__(256) void gconv_mfma(
    const ushort* __restrict__ xt,      // [16384][352]
    const ushort* __restrict__ Ab1,
    const ushort* __restrict__ Ab2,     // [336][352]
    const ushort* __restrict__ W1t,
    const ushort* __restrict__ W2t,     // [128][128]
    ushort* __restrict__ dout,          // L0: [41600][128] bf16
    const float* __restrict__ feature,  // L1: [325][32] fp32
    const float* __restrict__ Wp,       // L1: [160][2]
    const float* __restrict__ bp,       // L1: [2]
    float* __restrict__ out,            // L1: [41600][12][2]
    int t)
{
    __shared__ ushort m1s[32][136];
    __shared__ ushort m2s[32][136];
    __shared__ float  dfs[32][132];

    const int n0 = blockIdx.x * 16;
    const int col0 = blockIdx.y * 256;
    const int tid = threadIdx.x;
    const int w = tid >> 6, l = tid & 63, lr = l & 15, lk = l >> 4;

    f32x4 m1[4], m2[4];
    #pragma unroll
    for (int f = 0; f < 4; ++f) { m1[f] = (f32x4){0.f,0.f,0.f,0.f}; m2[f] = (f32x4){0.f,0.f,0.f,0.f}; }

    // GEMM1: K = 352 over nodes
    #pragma unroll 2
    for (int kk = 0; kk < KPAD / 32; ++kk) {
        const int kb = kk * 32 + lk * 8;
        bf16x8 a1 = *(const bf16x8*)(Ab1 + (size_t)(n0 + lr) * KPAD + kb);
        bf16x8 a2 = *(const bf16x8*)(Ab2 + (size_t)(n0 + lr) * KPAD + kb);
        #pragma unroll
        for (int f = 0; f < 4; ++f) {
            bf16x8 bx = *(const bf16x8*)(xt + (size_t)(col0 + w * 64 + f * 16 + lr) * KPAD + kb);
            m1[f] = MFMA(a1, bx, m1[f]);
            m2[f] = MFMA(a2, bx, m2[f]);
        }
    }

    // epilogue1 -> LDS (row2 = b_local*16 + n_local, K-fast over ch)
    #pragma unroll
    for (int f = 0; f < 4; ++f) {
        int colb = w * 64 + f * 16 + lr;
        int b_local = colb >> 7, chh = colb & 127;
        #pragma unroll
        for (int i = 0; i < 4; ++i) {
            int r2 = b_local * 16 + lk * 4 + i;
            m1s[r2][chh] = f2bf(m1[f][i]);
            m2s[r2][chh] = f2bf(m2[f][i]);
        }
    }
    __syncthreads();

    // GEMM2: M=32, N=128, K=128; D = m1@W1 + m2@W2
    f32x4 dacc[2][2];
    #pragma unroll
    for (int mf = 0; mf < 2; ++mf)
        #pragma unroll
        for (int nf = 0; nf < 2; ++nf) dacc[mf][nf] = (f32x4){0.f,0.f,0.f,0.f};

    #pragma unroll
    for (int kk = 0; kk < 4; ++kk) {
        const int kb = kk * 32 + lk * 8;
        bf16x8 a10 = *(const bf16x8*)&m1s[lr][kb];
        bf16x8 a11 = *(const bf16x8*)&m1s[16 + lr][kb];
        bf16x8 a20 = *(const bf16x8*)&m2s[lr][kb];
        bf16x8 a21 = *(const bf16x8*)&m2s[16 + lr][kb];
        #pragma unroll
        for (int nf = 0; nf < 2; ++nf) {
            int ncol = w * 32 + nf * 16 + lr;
            bf16x8 b1 = *(const bf16x8*)(W1t + (size_t)ncol * HHv + kb);
            bf16x8 b2 = *(const bf16x8*)(W2t + (size_t)ncol * HHv + kb);
            dacc[0][nf] = MFMA(a10, b1, dacc[0][nf]);
            dacc[0][nf] = MFMA(a20, b2, dacc[0][nf]);
            dacc[1][nf] = MFMA(a11, b1, dacc[1][nf]);
            dacc[1][nf] = MFMA(a21, b2, dacc[1][nf]);
        }
    }
    __syncthreads();

    if (LAYER == 0) {
        // store D bf16 to LDS then coalesced copy to dout
        #pragma unroll
        for (int mf = 0; mf < 2; ++mf)
            #pragma unroll
            for (int nf = 0; nf < 2; ++nf) {
                int cho = w * 32 + nf * 16 + lr;
                #pragma unroll
                for (int i = 0; i < 4; ++i) {
                    int r2 = mf * 16 + lk * 4 + i;
                    m1s[r2][cho] = f2bf(0.5f * dacc[mf][nf][i]);
                }
            }
        __syncthreads();
        {
            int r2 = tid >> 3, c0 = (tid & 7) * 16;
            int n_local = r2 & 15, b_local = r2 >> 4;
            int n = n0 + n_local;
            if (n < NN) {
                size_t r = (size_t)n * BBv + (blockIdx.y * 2 + b_local);
                *(ushort8*)(dout + r * HHv + c0)     = *(const ushort8*)&m1s[r2][c0];
                *(ushort8*)(dout + r * HHv + c0 + 8) = *(const ushort8*)&m1s[r2][c0 + 8];
            }
        }
    } else {
        // projection epilogue (fp32)
        #pragma unroll
        for (int mf = 0; mf < 2; ++mf)
            #pragma unroll
            for (int nf = 0; nf < 2; ++nf) {
                int cho = w * 32 + nf * 16 + lr;
                #pragma unroll
                for (int i = 0; i < 4; ++i) {
                    int r2 = mf * 16 + lk * 4 + i;
                    dfs[r2][cho] = 0.5f * dacc[mf][nf][i];
                }
            }
        __syncthreads();
        {
            int r2 = tid >> 3, sub = tid & 7;
            int n_local = r2 & 15, b_local = r2 >> 4;
            int n = n0 + n_local;
            if (n < NN) {
                float a0 = 0.f, a1 = 0.f;
                for (int kq = 0; kq < 20; ++kq) {
                    int k = sub * 20 + kq;
                    if (k < 160) {
                        float v = (k < HHv) ? dfs[r2][k] : feature[n * DFDv + (k - HHv)];
                        a0 = fmaf(v, Wp[k * 2 + 0], a0);
                        a1 = fmaf(v, Wp[k * 2 + 1], a1);
                    }
                }
                #pragma unroll
                for (int o = 4; o > 0; o >>= 1) {
                    a0 += __shfl_down(a0, o, 8);
                    a1 += __shfl_down(a1, o, 8);
                }
                if (sub == 0) {
                    size_t r = (size_t)n * BBv + (blockIdx.y * 2 + b_local);
                    out[(r * TTv + t) * ODDv + 0] = a0 + bp[0];
                    out[(r * TTv + t) * ODDv + 1] = a1 + bp[1];
                }
            }
        }
    }
}

// ---------------------------------------------------------------------------
extern "C" void kernel_launch(void* const* d_in, const int* in_sizes, int n_in,
                              void* d_out, int out_size, void* d_ws, size_t ws_size,
                              hipStream_t stream)
{
    const float* feature = (const float*)d_in[0];
    const float* label   = (const float*)d_in[1];
    const float* state0  = (const float*)d_in[2];
    const float* state1  = (const float*)d_in[3];
    const float* Wx0 = (const float*)d_in[4];
    const float* Wh0 = (const float*)d_in[5];
    const float* b0  = (const float*)d_in[6];
    const float* Wx1 = (const float*)d_in[7];
    const float* Wh1 = (const float*)d_in[8];
    const float* b1  = (const float*)d_in[9];
    const float* A01 = (const float*)d_in[10];
    const float* A02 = (const float*)d_in[11];
    const float* Wg01 = (const float*)d_in[12];
    const float* Wg02 = (const float*)d_in[13];
    const float* A11 = (const float*)d_in[14];
    const float* A12 = (const float*)d_in[15];
    const float* Wg11 = (const float*)d_in[16];
    const float* Wg12 = (const float*)d_in[17];
    const float* Wp  = (const float*)d_in[18];
    const float* bp  = (const float*)d_in[19];

    float* out = (float*)d_out;

    char* p = (char*)d_ws;
    auto alloc = [&](size_t bytes) {
        void* r = (void*)p; p += (bytes + 255) & ~(size_t)255; return r;
    };
    float*  h0   = (float*) alloc((size_t)MROWS * HHv * 4);
    float*  h1   = (float*) alloc((size_t)MROWS * HHv * 4);
    ushort* d0   = (ushort*)alloc((size_t)MROWS * HHv * 2);
    ushort* xt0  = (ushort*)alloc((size_t)BBv * HHv * KPAD * 2);
    ushort* xt1  = (ushort*)alloc((size_t)BBv * HHv * KPAD * 2);
    ushort* Ab01 = (ushort*)alloc((size_t)NPAD * KPAD * 2);
    ushort* Ab02 = (ushort*)alloc((size_t)NPAD * KPAD * 2);
    ushort* Ab11 = (ushort*)alloc((size_t)NPAD * KPAD * 2);
    ushort* Ab12 = (ushort*)alloc((size_t)NPAD * KPAD * 2);
    ushort* Wx0t = (ushort*)alloc((size_t)G3v * 64 * 2);
    ushort* Wh0t = (ushort*)alloc((size_t)G3v * HHv * 2);
    ushort* Wx1t = (ushort*)alloc((size_t)G3v * 160 * 2);
    ushort* Wh1t = (ushort*)alloc((size_t)G3v * HHv * 2);
    ushort* Wg01t = (ushort*)alloc((size_t)HHv * HHv * 2);
    ushort* Wg02t = (ushort*)alloc((size_t)HHv * HHv * 2);
    ushort* Wg11t = (ushort*)alloc((size_t)HHv * HHv * 2);
    ushort* Wg12t = (ushort*)alloc((size_t)HHv * HHv * 2);
    ushort* featb = (ushort*)alloc((size_t)NPAD * DFDv * 2);

    hipMemcpyAsync(h0, state0, (size_t)MROWS * HHv * 4, hipMemcpyDeviceToDevice, stream);
    hipMemcpyAsync(h1, state1, (size_t)MROWS * HHv * 4, hipMemcpyDeviceToDevice, stream);

    auto cdiv = [](int a, int b) { return (a + b - 1) / b; };
    wtrans_kernel<<<cdiv(G3v * 64, 256), 256, 0, stream>>>(Wx0, Wx0t, 36, G3v, 64);
    wtrans_kernel<<<cdiv(G3v * HHv, 256), 256, 0, stream>>>(Wh0, Wh0t, HHv, G3v, HHv);
    wtrans_kernel<<<cdiv(G3v * 160, 256), 256, 0, stream>>>(Wx1, Wx1t, 160, G3v, 160);
    wtrans_kernel<<<cdiv(G3v * HHv, 256), 256, 0, stream>>>(Wh1, Wh1t, HHv, G3v, HHv);
    wtrans_kernel<<<cdiv(HHv * HHv, 256), 256, 0, stream>>>(Wg01, Wg01t, HHv, HHv, HHv);
    wtrans_kernel<<<cdiv(HHv * HHv, 256), 256, 0, stream>>>(Wg02, Wg02t, HHv, HHv, HHv);
    wtrans_kernel<<<cdiv(HHv * HHv, 256), 256, 0, stream>>>(Wg11, Wg11t, HHv, HHv, HHv);
    wtrans_kernel<<<cdiv(HHv * HHv, 256), 256, 0, stream>>>(Wg12, Wg12t, HHv, HHv, HHv);
    aconv_kernel<<<cdiv(NPAD * KPAD, 256), 256, 0, stream>>>(A01, Ab01);
    aconv_kernel<<<cdiv(NPAD * KPAD, 256), 256, 0, stream>>>(A02, Ab02);
    aconv_kernel<<<cdiv(NPAD * KPAD, 256), 256, 0, stream>>>(A11, Ab11);
    aconv_kernel<<<cdiv(NPAD * KPAD, 256), 256, 0, stream>>>(A12, Ab12);
    fconv_kernel<<<cdiv(NPAD * DFDv, 256), 256, 0, stream>>>(feature, featb);

    const dim3 gruGrid(11, BBv);
    const dim3 gcGrid(21, 64);

    for (int t = 0; t < TTv; ++t) {
        gru_mfma<64, 0><<<gruGrid, 512, 0, stream>>>(
            h0, nullptr, out, label, featb, Wx0t, Wh0t, b0, xt0, t);
        gconv_mfma<0><<<gcGrid, 256, 0, stream>>>(
            xt0, Ab01, Ab02, Wg01t, Wg02t, d0, nullptr, nullptr, nullptr, nullptr, t);
        gru_mfma<160, 1><<<gruGrid, 512, 0, stream>>>(
            h1, d0, nullptr, nullptr, featb, Wx1t, Wh1t, b1, xt1, t);
        gconv_mfma<1><<<gcGrid, 256, 0, stream>>>(
            xt1, Ab11, Ab12, Wg11t, Wg12t, nullptr, feature, Wp, bp, out, t);
    }
}

// Round 4
// 2268.396 us; speedup vs baseline: 9.6588x; 1.0981x over previous
//
#include <hip/hip_runtime.h>
#include <math.h>

#define NN 325
#define NPAD 336     // n padded for A rows (16-mult)
#define KPAD 352     // node dim padded for K loop (32-mult)
#define BBv 128
#define TTv 12
#define HHv 128
#define DFDv 32
#define ODDv 2
#define MROWS (NN*BBv)   // 41600
#define G3v 384

typedef __attribute__((ext_vector_type(8))) short bf16x8;
typedef __attribute__((ext_vector_type(4))) float f32x4;
typedef __attribute__((ext_vector_type(8))) unsigned short ushort8;
typedef unsigned short ushort;

__device__ __forceinline__ ushort f2bf(float f) {
    union { float f; unsigned u; } v; v.f = f;
    unsigned r = v.u + 0x7FFFu + ((v.u >> 16) & 1u);
    return (ushort)(r >> 16);
}
__device__ __forceinline__ float bf2f(ushort u) {
    union { unsigned u; float f; } v; v.u = ((unsigned)u) << 16; return v.f;
}
__device__ __forceinline__ float sigmoidf_(float x) { return 1.0f / (1.0f + __expf(-x)); }

#define MFMA(a,b,c) __builtin_amdgcn_mfma_f32_16x16x32_bf16((a),(b),(c),0,0,0)

// ---------------------------------------------------------------------------
// setup converters
// ---------------------------------------------------------------------------
__global__ void wtrans_kernel(const float* __restrict__ W, ushort* __restrict__ Wt,
                              int K, int N, int KP) {
    int idx = blockIdx.x * 256 + threadIdx.x;
    if (idx >= N * KP) return;
    int n = idx / KP, k = idx - n * KP;
    Wt[idx] = f2bf(k < K ? W[(size_t)k * N + n] : 0.f);
}
__global__ void aconv_kernel(const float* __restrict__ A, ushort* __restrict__ Ab) {
    int idx = blockIdx.x * 256 + threadIdx.x;
    if (idx >= NPAD * KPAD) return;
    int n = idx / KPAD, m = idx - n * KPAD;
    Ab[idx] = f2bf((n < NN && m < NN) ? A[n * NN + m] : 0.f);
}
__global__ void fconv_kernel(const float* __restrict__ F, ushort* __restrict__ Fb) {
    int idx = blockIdx.x * 256 + threadIdx.x;
    if (idx >= NPAD * DFDv) return;
    int n = idx >> 5, c = idx & 31;
    Fb[idx] = f2bf(n < NN ? F[n * DFDv + c] : 0.f);
}
// state fp32 [n][b][ch] -> transposed bf16 xt[(b*128+ch)][node]
__global__ void strans_kernel(const float* __restrict__ S, ushort* __restrict__ xt) {
    int idx = blockIdx.x * 256 + threadIdx.x;
    if (idx >= BBv * HHv * KPAD) return;
    int col = idx / KPAD, n = idx - col * KPAD;
    int b = col >> 7, ch = col & 127;
    xt[idx] = (n < NN) ? f2bf(S[((size_t)n * BBv + b) * HHv + ch]) : (ushort)0;
}

// ---------------------------------------------------------------------------
// Prologue GRU (t=0 only, layer 0): h fp32 state, writes xt0 transposed bf16.
// ---------------------------------------------------------------------------
template<int KP>
__global__ __launch_bounds__(512) void gru_mfma(
    float* __restrict__ h,
    const float* __restrict__ label,
    const ushort* __restrict__ featb,
    const ushort* __restrict__ Wxt,
    const ushort* __restrict__ Wht,
    const float* __restrict__ bias,
    ushort* __restrict__ xt)
{
    __shared__ ushort hs[32][136];
    __shared__ ushort xs[32][KP + 8];
    __shared__ ushort hnb[32][136];

    const int n0 = blockIdx.x * 32;
    const int b  = blockIdx.y;
    const int tid = threadIdx.x;

    {
        int i = tid >> 4, c0 = (tid & 15) * 8;
        int n = n0 + i; if (n > NN - 1) n = NN - 1;
        const float* src = h + ((size_t)(n * BBv + b) * HHv + c0);
        float4 v0 = *(const float4*)src;
        float4 v1 = *(const float4*)(src + 4);
        ushort* dst = &hs[i][c0];
        dst[0]=f2bf(v0.x); dst[1]=f2bf(v0.y); dst[2]=f2bf(v0.z); dst[3]=f2bf(v0.w);
        dst[4]=f2bf(v1.x); dst[5]=f2bf(v1.y); dst[6]=f2bf(v1.z); dst[7]=f2bf(v1.w);
    }
    // t = 0: data part zero; only feat present
    for (int e = tid; e < 32 * KP; e += 512) {
        int i = e / KP, k = e - i * KP;
        int n = n0 + i; if (n > NN - 1) n = NN - 1;
        ushort v = 0;
        if (k >= 4 && k < 36) v = featb[n * DFDv + (k - 4)];
        xs[i][k] = v;
    }
    __syncthreads();

    const int w = tid >> 6, l = tid & 63;
    const int lr = l & 15, lk = l >> 4;

    f32x4 az[2], ar[2], agc[2], ahc[2];
    #pragma unroll
    for (int m = 0; m < 2; ++m) {
        az[m] = (f32x4){0.f,0.f,0.f,0.f}; ar[m] = (f32x4){0.f,0.f,0.f,0.f};
        agc[m] = (f32x4){0.f,0.f,0.f,0.f}; ahc[m] = (f32x4){0.f,0.f,0.f,0.f};
    }

    #pragma unroll
    for (int kk = 0; kk < KP / 32; ++kk) {
        const int kb = kk * 32 + lk * 8;
        bf16x8 a0 = *(const bf16x8*)&xs[lr][kb];
        bf16x8 a1 = *(const bf16x8*)&xs[16 + lr][kb];
        bf16x8 bz = *(const bf16x8*)(Wxt + (size_t)(w * 16 + lr) * KP + kb);
        bf16x8 br = *(const bf16x8*)(Wxt + (size_t)(128 + w * 16 + lr) * KP + kb);
        bf16x8 bc = *(const bf16x8*)(Wxt + (size_t)(256 + w * 16 + lr) * KP + kb);
        az[0] = MFMA(a0, bz, az[0]); az[1] = MFMA(a1, bz, az[1]);
        ar[0] = MFMA(a0, br, ar[0]); ar[1] = MFMA(a1, br, ar[1]);
        agc[0] = MFMA(a0, bc, agc[0]); agc[1] = MFMA(a1, bc, agc[1]);
    }
    #pragma unroll
    for (int kk = 0; kk < 4; ++kk) {
        const int kb = kk * 32 + lk * 8;
        bf16x8 a0 = *(const bf16x8*)&hs[lr][kb];
        bf16x8 a1 = *(const bf16x8*)&hs[16 + lr][kb];
        bf16x8 bz = *(const bf16x8*)(Wht + (size_t)(w * 16 + lr) * HHv + kb);
        bf16x8 br = *(const bf16x8*)(Wht + (size_t)(128 + w * 16 + lr) * HHv + kb);
        bf16x8 bc = *(const bf16x8*)(Wht + (size_t)(256 + w * 16 + lr) * HHv + kb);
        az[0] = MFMA(a0, bz, az[0]); az[1] = MFMA(a1, bz, az[1]);
        ar[0] = MFMA(a0, br, ar[0]); ar[1] = MFMA(a1, br, ar[1]);
        ahc[0] = MFMA(a0, bc, ahc[0]); ahc[1] = MFMA(a1, bc, ahc[1]);
    }

    const int ch = w * 16 + lr;
    const float bzv = bias[ch], brv = bias[128 + ch], bcv = bias[256 + ch];
    #pragma unroll
    for (int m = 0; m < 2; ++m)
        #pragma unroll
        for (int i = 0; i < 4; ++i) {
            int r2 = m * 16 + lk * 4 + i;
            float z  = sigmoidf_(az[m][i] + bzv);
            float rr = sigmoidf_(ar[m][i] + brv);
            float c  = tanhf(agc[m][i] + bcv + rr * ahc[m][i]);
            float hold = bf2f(hs[r2][ch]);
            float hn = z * hold + (1.f - z) * c;
            hnb[r2][ch] = f2bf(hn);
        }
    __syncthreads();

    {
        int chx = tid >> 2, g = tid & 3;
        ushort8 v;
        #pragma unroll
        for (int k = 0; k < 8; ++k) v[k] = hnb[g * 8 + k][chx];
        *(ushort8*)(xt + (size_t)(b * HHv + chx) * KPAD + n0 + g * 8) = v;
    }
}

// ---------------------------------------------------------------------------
// Fused step kernel.
// WHICH=0 (K_A): gconv0(xtB=h0[t]) -> d -> GRU1(h1-old=xtH) -> xtO=h1[t]
// WHICH=1 (K_B): gconv1(xtB=h1[t]) -> d -> proj out[t] -> GRU0(h0-old=xtH,
//                x=[out[t],aux[t],feat]) -> xtO=h0[t+1]
// Block: 16 nodes x 2 batches (32 rows), 512 threads = 8 waves.
// ---------------------------------------------------------------------------
template<int WHICH>
__global__ __launch_bounds__(512) void fused_step(
    const ushort* __restrict__ xtB,
    const ushort* __restrict__ xtH,
    ushort* __restrict__ xtO,
    const ushort* __restrict__ Ab1,
    const ushort* __restrict__ Ab2,
    const ushort* __restrict__ W1t,
    const ushort* __restrict__ W2t,
    const ushort* __restrict__ Wxt,
    const ushort* __restrict__ Wht,
    const float* __restrict__ bias,
    const ushort* __restrict__ featb,
    const float* __restrict__ label,
    const float* __restrict__ Wp,
    const float* __restrict__ bp,
    float* __restrict__ out,
    int t)
{
    constexpr int KXP = (WHICH == 0) ? 160 : 64;
    __shared__ ushort m1s[32][136];
    __shared__ ushort m2s[32][136];
    __shared__ ushort hs[32][136];
    __shared__ ushort xs[32][KXP + 8];
    __shared__ float  os[32][2];

    const int n0 = blockIdx.x * 16;
    const int b0 = blockIdx.y * 2;
    const int tid = threadIdx.x;
    const int w = tid >> 6, l = tid & 63, lr = l & 15, lk = l >> 4;

    // ---- phase 0: stage h-old (transpose from xtH) ----
    {
        int chg = tid >> 1, g = tid & 1;
        int bl = chg >> 7, ch = chg & 127;
        ushort8 v = *(const ushort8*)(xtH + (size_t)((b0 + bl) * HHv + ch) * KPAD + n0 + g * 8);
        #pragma unroll
        for (int k = 0; k < 8; ++k) hs[bl * 16 + g * 8 + k][ch] = v[k];
    }
    if (WHICH == 0) {
        // xs feat part (k = 128..159)
        for (int e = tid; e < 32 * 32; e += 512) {
            int r2 = e >> 5, k = e & 31;
            int n = n0 + (r2 & 15); if (n > NN - 1) n = NN - 1;
            xs[r2][128 + k] = featb[n * DFDv + k];
        }
    }

    // ---- phase 1: GEMM1  m1 = A1*X, m2 = A2*X  (16n x 256 cols, K=352) ----
    f32x4 m1[2], m2[2];
    #pragma unroll
    for (int f = 0; f < 2; ++f) { m1[f] = (f32x4){0.f,0.f,0.f,0.f}; m2[f] = (f32x4){0.f,0.f,0.f,0.f}; }

    #pragma unroll 2
    for (int kk = 0; kk < KPAD / 32; ++kk) {
        const int kb = kk * 32 + lk * 8;
        bf16x8 a1 = *(const bf16x8*)(Ab1 + (size_t)(n0 + lr) * KPAD + kb);
        bf16x8 a2 = *(const bf16x8*)(Ab2 + (size_t)(n0 + lr) * KPAD + kb);
        #pragma unroll
        for (int f = 0; f < 2; ++f) {
            bf16x8 bx = *(const bf16x8*)(xtB + (size_t)(b0 * HHv + w * 32 + f * 16 + lr) * KPAD + kb);
            m1[f] = MFMA(a1, bx, m1[f]);
            m2[f] = MFMA(a2, bx, m2[f]);
        }
    }
    #pragma unroll
    for (int f = 0; f < 2; ++f) {
        int colg = w * 32 + f * 16 + lr;
        int bl = colg >> 7, ch = colg & 127;
        #pragma unroll
        for (int i = 0; i < 4; ++i) {
            int r2 = bl * 16 + lk * 4 + i;
            m1s[r2][ch] = f2bf(m1[f][i]);
            m2s[r2][ch] = f2bf(m2[f][i]);
        }
    }
    __syncthreads();

    // ---- phase 2: GEMM2  d = 0.5*(m1@W1 + m2@W2)  (32 x 128, K=128) ----
    f32x4 dacc[2];
    dacc[0] = (f32x4){0.f,0.f,0.f,0.f}; dacc[1] = (f32x4){0.f,0.f,0.f,0.f};
    #pragma unroll
    for (int kk = 0; kk < 4; ++kk) {
        const int kb = kk * 32 + lk * 8;
        bf16x8 a10 = *(const bf16x8*)&m1s[lr][kb];
        bf16x8 a11 = *(const bf16x8*)&m1s[16 + lr][kb];
        bf16x8 a20 = *(const bf16x8*)&m2s[lr][kb];
        bf16x8 a21 = *(const bf16x8*)&m2s[16 + lr][kb];
        bf16x8 b1 = *(const bf16x8*)(W1t + (size_t)(w * 16 + lr) * HHv + kb);
        bf16x8 b2 = *(const bf16x8*)(W2t + (size_t)(w * 16 + lr) * HHv + kb);
        dacc[0] = MFMA(a10, b1, dacc[0]); dacc[0] = MFMA(a20, b2, dacc[0]);
        dacc[1] = MFMA(a11, b1, dacc[1]); dacc[1] = MFMA(a21, b2, dacc[1]);
    }
    __syncthreads();   // all GEMM2 reads of m1s/m2s done

    if (WHICH == 0) {
        // d -> xs[k=0..127] (A-layout for GRU x@Wx)
        #pragma unroll
        for (int m = 0; m < 2; ++m)
            #pragma unroll
            for (int i = 0; i < 4; ++i)
                xs[m * 16 + lk * 4 + i][w * 16 + lr] = f2bf(0.5f * dacc[m][i]);
        __syncthreads();
    } else {
        // d -> m1s (for projection)
        #pragma unroll
        for (int m = 0; m < 2; ++m)
            #pragma unroll
            for (int i = 0; i < 4; ++i)
                m1s[m * 16 + lk * 4 + i][w * 16 + lr] = f2bf(0.5f * dacc[m][i]);
        __syncthreads();

        // ---- projection: out = [d | feat] @ Wp + bp ----
        {
            int r2p = tid >> 4, sub = tid & 15;
            int n = n0 + (r2p & 15); int nc = (n > NN - 1) ? NN - 1 : n;
            float a0 = 0.f, a1 = 0.f;
            #pragma unroll
            for (int q = 0; q < 10; ++q) {
                int k = sub * 10 + q;
                float v = (k < HHv) ? bf2f(m1s[r2p][k]) : bf2f(featb[nc * DFDv + (k - HHv)]);
                a0 = fmaf(v, Wp[k * 2 + 0], a0);
                a1 = fmaf(v, Wp[k * 2 + 1], a1);
            }
            #pragma unroll
            for (int o = 8; o > 0; o >>= 1) {
                a0 += __shfl_down(a0, o, 16);
                a1 += __shfl_down(a1, o, 16);
            }
            if (sub == 0) { os[r2p][0] = a0 + bp[0]; os[r2p][1] = a1 + bp[1]; }
        }
        __syncthreads();

        // write out[t] + build xs = [out(2) | aux(2) | feat(32) | 0pad]
        if (tid < 64) {
            int r2 = tid >> 1, c = tid & 1;
            int n = n0 + (r2 & 15), b = b0 + (r2 >> 4);
            if (n < NN)
                out[(((size_t)n * BBv + b) * TTv + t) * ODDv + c] = os[r2][c];
        }
        for (int e = tid; e < 32 * 64; e += 512) {
            int r2 = e >> 6, k = e & 63;
            int n = n0 + (r2 & 15), b = b0 + (r2 >> 4);
            int nc = (n > NN - 1) ? NN - 1 : n;
            ushort v;
            if (k < 2)        v = f2bf(os[r2][k]);
            else if (k < 4)   v = f2bf(label[(((size_t)nc * BBv + b) * TTv + t) * 4 + 2 + (k - 2)]);
            else if (k < 36)  v = featb[nc * DFDv + (k - 4)];
            else              v = 0;
            xs[r2][k] = v;
        }
        __syncthreads();
    }

    // ---- phase 3: GRU  (M=32 rows, N=384 gates) ----
    f32x4 az[2], ar[2], agc[2], ahc[2];
    #pragma unroll
    for (int m = 0; m < 2; ++m) {
        az[m] = (f32x4){0.f,0.f,0.f,0.f}; ar[m] = (f32x4){0.f,0.f,0.f,0.f};
        agc[m] = (f32x4){0.f,0.f,0.f,0.f}; ahc[m] = (f32x4){0.f,0.f,0.f,0.f};
    }

    #pragma unroll
    for (int kk = 0; kk < KXP / 32; ++kk) {
        const int kb = kk * 32 + lk * 8;
        bf16x8 a0 = *(const bf16x8*)&xs[lr][kb];
        bf16x8 a1 = *(const bf16x8*)&xs[16 + lr][kb];
        bf16x8 bz = *(const bf16x8*)(Wxt + (size_t)(w * 16 + lr) * KXP + kb);
        bf16x8 br = *(const bf16x8*)(Wxt + (size_t)(128 + w * 16 + lr) * KXP + kb);
        bf16x8 bc = *(const bf16x8*)(Wxt + (size_t)(256 + w * 16 + lr) * KXP + kb);
        az[0] = MFMA(a0, bz, az[0]); az[1] = MFMA(a1, bz, az[1]);
        ar[0] = MFMA(a0, br, ar[0]); ar[1] = MFMA(a1, br, ar[1]);
        agc[0] = MFMA(a0, bc, agc[0]); agc[1] = MFMA(a1, bc, agc[1]);
    }
    #pragma unroll
    for (int kk = 0; kk < 4; ++kk) {
        const int kb = kk * 32 + lk * 8;
        bf16x8 a0 = *(const bf16x8*)&hs[lr][kb];
        bf16x8 a1 = *(const bf16x8*)&hs[16 + lr][kb];
        bf16x8 bz = *(const bf16x8*)(Wht + (size_t)(w * 16 + lr) * HHv + kb);
        bf16x8 br = *(const bf16x8*)(Wht + (size_t)(128 + w * 16 + lr) * HHv + kb);
        bf16x8 bc = *(const bf16x8*)(Wht + (size_t)(256 + w * 16 + lr) * HHv + kb);
        az[0] = MFMA(a0, bz, az[0]); az[1] = MFMA(a1, bz, az[1]);
        ar[0] = MFMA(a0, br, ar[0]); ar[1] = MFMA(a1, br, ar[1]);
        ahc[0] = MFMA(a0, bc, ahc[0]); ahc[1] = MFMA(a1, bc, ahc[1]);
    }

    // ---- gating (stage h-new into m2s, free after GEMM2) ----
    {
        const int ch = w * 16 + lr;
        const float bzv = bias[ch], brv = bias[128 + ch], bcv = bias[256 + ch];
        #pragma unroll
        for (int m = 0; m < 2; ++m)
            #pragma unroll
            for (int i = 0; i < 4; ++i) {
                int r2 = m * 16 + lk * 4 + i;
                float z  = sigmoidf_(az[m][i] + bzv);
                float rr = sigmoidf_(ar[m][i] + brv);
                float c  = tanhf(agc[m][i] + bcv + rr * ahc[m][i]);
                float hold = bf2f(hs[r2][ch]);
                float hn = z * hold + (1.f - z) * c;
                m2s[r2][ch] = f2bf(hn);
            }
    }
    __syncthreads();

    // ---- write h-new transposed to xtO ----
    {
        int chg = tid >> 1, g = tid & 1;
        int bl = chg >> 7, ch = chg & 127;
        ushort8 v;
        #pragma unroll
        for (int k = 0; k < 8; ++k) v[k] = m2s[bl * 16 + g * 8 + k][ch];
        *(ushort8*)(xtO + (size_t)((b0 + bl) * HHv + ch) * KPAD + n0 + g * 8) = v;
    }
}

// ---------------------------------------------------------------------------
extern "C" void kernel_launch(void* const* d_in, const int* in_sizes, int n_in,
                              void* d_out, int out_size, void* d_ws, size_t ws_size,
                              hipStream_t stream)
{
    const float* feature = (const float*)d_in[0];
    const float* label   = (const float*)d_in[1];
    const float* state0  = (const float*)d_in[2];
    const float* state1  = (const float*)d_in[3];
    const float* Wx0 = (const float*)d_in[4];
    const float* Wh0 = (const float*)d_in[5];
    const float* b0  = (const float*)d_in[6];
    const float* Wx1 = (const float*)d_in[7];
    const float* Wh1 = (const float*)d_in[8];
    const float* b1  = (const float*)d_in[9];
    const float* A01 = (const float*)d_in[10];
    const float* A02 = (const float*)d_in[11];
    const float* Wg01 = (const float*)d_in[12];
    const float* Wg02 = (const float*)d_in[13];
    const float* A11 = (const float*)d_in[14];
    const float* A12 = (const float*)d_in[15];
    const float* Wg11 = (const float*)d_in[16];
    const float* Wg12 = (const float*)d_in[17];
    const float* Wp  = (const float*)d_in[18];
    const float* bp  = (const float*)d_in[19];

    float* out = (float*)d_out;

    char* p = (char*)d_ws;
    auto alloc = [&](size_t bytes) {
        void* r = (void*)p; p += (bytes + 255) & ~(size_t)255; return r;
    };
    const size_t XTSZ = (size_t)BBv * HHv * KPAD;   // 5.77M elems
    ushort* xt0[2] = { (ushort*)alloc(XTSZ * 2), (ushort*)alloc(XTSZ * 2) };
    ushort* xt1[2] = { (ushort*)alloc(XTSZ * 2), (ushort*)alloc(XTSZ * 2) };
    float*  h0s  = (float*) alloc((size_t)MROWS * HHv * 4);
    ushort* Ab01 = (ushort*)alloc((size_t)NPAD * KPAD * 2);
    ushort* Ab02 = (ushort*)alloc((size_t)NPAD * KPAD * 2);
    ushort* Ab11 = (ushort*)alloc((size_t)NPAD * KPAD * 2);
    ushort* Ab12 = (ushort*)alloc((size_t)NPAD * KPAD * 2);
    ushort* Wx0t = (ushort*)alloc((size_t)G3v * 64 * 2);
    ushort* Wh0t = (ushort*)alloc((size_t)G3v * HHv * 2);
    ushort* Wx1t = (ushort*)alloc((size_t)G3v * 160 * 2);
    ushort* Wh1t = (ushort*)alloc((size_t)G3v * HHv * 2);
    ushort* Wg01t = (ushort*)alloc((size_t)HHv * HHv * 2);
    ushort* Wg02t = (ushort*)alloc((size_t)HHv * HHv * 2);
    ushort* Wg11t = (ushort*)alloc((size_t)HHv * HHv * 2);
    ushort* Wg12t = (ushort*)alloc((size_t)HHv * HHv * 2);
    ushort* featb = (ushort*)alloc((size_t)NPAD * DFDv * 2);

    hipMemcpyAsync(h0s, state0, (size_t)MROWS * HHv * 4, hipMemcpyDeviceToDevice, stream);

    auto cdiv = [](int a, int b) { return (a + b - 1) / b; };
    wtrans_kernel<<<cdiv(G3v * 64, 256), 256, 0, stream>>>(Wx0, Wx0t, 36, G3v, 64);
    wtrans_kernel<<<cdiv(G3v * HHv, 256), 256, 0, stream>>>(Wh0, Wh0t, HHv, G3v, HHv);
    wtrans_kernel<<<cdiv(G3v * 160, 256), 256, 0, stream>>>(Wx1, Wx1t, 160, G3v, 160);
    wtrans_kernel<<<cdiv(G3v * HHv, 256), 256, 0, stream>>>(Wh1, Wh1t, HHv, G3v, HHv);
    wtrans_kernel<<<cdiv(HHv * HHv, 256), 256, 0, stream>>>(Wg01, Wg01t, HHv, HHv, HHv);
    wtrans_kernel<<<cdiv(HHv * HHv, 256), 256, 0, stream>>>(Wg02, Wg02t, HHv, HHv, HHv);
    wtrans_kernel<<<cdiv(HHv * HHv, 256), 256, 0, stream>>>(Wg11, Wg11t, HHv, HHv, HHv);
    wtrans_kernel<<<cdiv(HHv * HHv, 256), 256, 0, stream>>>(Wg12, Wg12t, HHv, HHv, HHv);
    aconv_kernel<<<cdiv(NPAD * KPAD, 256), 256, 0, stream>>>(A01, Ab01);
    aconv_kernel<<<cdiv(NPAD * KPAD, 256), 256, 0, stream>>>(A02, Ab02);
    aconv_kernel<<<cdiv(NPAD * KPAD, 256), 256, 0, stream>>>(A11, Ab11);
    aconv_kernel<<<cdiv(NPAD * KPAD, 256), 256, 0, stream>>>(A12, Ab12);
    fconv_kernel<<<cdiv(NPAD * DFDv, 256), 256, 0, stream>>>(feature, featb);
    strans_kernel<<<cdiv((int)XTSZ, 256), 256, 0, stream>>>(state1, xt1[0]);

    // prologue: h0[0] = GRU0(data=0, state0) -> xt0[0]
    gru_mfma<64><<<dim3(11, BBv), 512, 0, stream>>>(h0s, label, featb, Wx0t, Wh0t, b0, xt0[0]);

    const dim3 grid(21, 64);
    for (int t = 0; t < TTv; ++t) {
        // K_A: gconv0(h0[t]) + GRU1 -> h1[t]
        fused_step<0><<<grid, 512, 0, stream>>>(
            xt0[t & 1], xt1[t & 1], xt1[(t + 1) & 1],
            Ab01, Ab02, Wg01t, Wg02t, Wx1t, Wh1t, b1, featb,
            nullptr, nullptr, nullptr, nullptr, t);
        // K_B: gconv1(h1[t]) + proj(out[t]) + GRU0 -> h0[t+1]
        fused_step<1><<<grid, 512, 0, stream>>>(
            xt1[(t + 1) & 1], xt0[t & 1], xt0[(t + 1) & 1],
            Ab11, Ab12, Wg11t, Wg12t, Wx0t, Wh0t, b0, featb,
            label, Wp, bp, out, t);
    }
}

// Round 5
// 1810.096 us; speedup vs baseline: 12.1044x; 1.2532x over previous
//
#include <hip/hip_runtime.h>
#include <math.h>

#define NN 325
#define NPAD 352     // n padded (32-mult)
#define KPAD 352     // node dim padded for K loop
#define BBv 128
#define TTv 12
#define HHv 128
#define DFDv 32
#define ODDv 2
#define G3v 384
#define GX 11
#define GY 64

typedef __attribute__((ext_vector_type(8))) short bf16x8;
typedef __attribute__((ext_vector_type(4))) float f32x4;
typedef __attribute__((ext_vector_type(8))) unsigned short ushort8;
typedef unsigned short ushort;

__device__ __forceinline__ ushort f2bf(float f) {
    union { float f; unsigned u; } v; v.f = f;
    unsigned r = v.u + 0x7FFFu + ((v.u >> 16) & 1u);
    return (ushort)(r >> 16);
}
__device__ __forceinline__ float bf2f(ushort u) {
    union { unsigned u; float f; } v; v.u = ((unsigned)u) << 16; return v.f;
}
__device__ __forceinline__ float sigmoidf_(float x) { return 1.0f / (1.0f + __expf(-x)); }

#define MFMA(a,b,c) __builtin_amdgcn_mfma_f32_16x16x32_bf16((a),(b),(c),0,0,0)

// ---------------------------------------------------------------------------
// setup kernels (once per launch)
// ---------------------------------------------------------------------------
__global__ void wtrans_kernel(const float* __restrict__ W, ushort* __restrict__ Wt,
                              int K, int N, int KP) {
    int idx = blockIdx.x * 256 + threadIdx.x;
    if (idx >= N * KP) return;
    int n = idx / KP, k = idx - n * KP;
    Wt[idx] = f2bf(k < K ? W[(size_t)k * N + n] : 0.f);
}
__global__ void aconv_kernel(const float* __restrict__ A, ushort* __restrict__ Ab) {
    int idx = blockIdx.x * 256 + threadIdx.x;
    if (idx >= NPAD * KPAD) return;
    int n = idx / KPAD, m = idx - n * KPAD;
    Ab[idx] = f2bf((n < NN && m < NN) ? A[n * NN + m] : 0.f);
}
// state fp32 [n][b][ch] -> transposed bf16 xt[(b*128+ch)][node]
__global__ void strans_kernel(const float* __restrict__ S, ushort* __restrict__ xt) {
    int idx = blockIdx.x * 256 + threadIdx.x;
    if (idx >= BBv * HHv * KPAD) return;
    int col = idx / KPAD, n = idx - col * KPAD;
    int b = col >> 7, ch = col & 127;
    xt[idx] = (n < NN) ? f2bf(S[((size_t)n * BBv + b) * HHv + ch]) : (ushort)0;
}
// gxf[n][j] = bias[j] + sum_k feat[n][k] * W[(row0+k)*384 + j]   (fp32)
__global__ void gxf_kernel(const float* __restrict__ W, const float* __restrict__ bias,
                           const float* __restrict__ feat, float* __restrict__ gxf, int row0) {
    int n = blockIdx.x, j = threadIdx.x;
    int nc = (n < NN) ? n : NN - 1;
    float a = bias[j];
    #pragma unroll 8
    for (int k = 0; k < DFDv; ++k) a = fmaf(feat[nc * DFDv + k], W[(size_t)(row0 + k) * G3v + j], a);
    gxf[(size_t)n * G3v + j] = a;
}
// pfeat[n][c] = bp[c] + sum_k feat[n][k] * Wp[(128+k)*2 + c]
__global__ void pfeat_kernel(const float* __restrict__ Wp, const float* __restrict__ bp,
                             const float* __restrict__ feat, float* __restrict__ pf) {
    int n = blockIdx.x, c = threadIdx.x;
    if (c >= 2) return;
    int nc = (n < NN) ? n : NN - 1;
    float a = bp[c];
    #pragma unroll 8
    for (int k = 0; k < DFDv; ++k) a = fmaf(feat[nc * DFDv + k], Wp[(size_t)(HHv + k) * ODDv + c], a);
    pf[n * 2 + c] = a;
}

// ---------------------------------------------------------------------------
// Prologue GRU0 at t=0: x-data = 0, so g_x = gxf0. 32 rows x 1 b per block.
// ---------------------------------------------------------------------------
__global__ __launch_bounds__(512) void gru0_init(
    const float* __restrict__ state0,
    const float* __restrict__ gxf0,     // [352][384] fp32 (incl bias)
    const ushort* __restrict__ Wht,     // [384][128]
    ushort* __restrict__ xt)
{
    __shared__ ushort hs[32][136];
    __shared__ ushort hnb[32][136];
    const int n0 = blockIdx.x * 32;
    const int b  = blockIdx.y;
    const int tid = threadIdx.x;
    {
        int i = tid >> 4, c0 = (tid & 15) * 8;
        int n = n0 + i; if (n > NN - 1) n = NN - 1;
        const float* src = state0 + ((size_t)(n * BBv + b) * HHv + c0);
        float4 v0 = *(const float4*)src;
        float4 v1 = *(const float4*)(src + 4);
        ushort* dst = &hs[i][c0];
        dst[0]=f2bf(v0.x); dst[1]=f2bf(v0.y); dst[2]=f2bf(v0.z); dst[3]=f2bf(v0.w);
        dst[4]=f2bf(v1.x); dst[5]=f2bf(v1.y); dst[6]=f2bf(v1.z); dst[7]=f2bf(v1.w);
    }
    __syncthreads();

    const int w = tid >> 6, l = tid & 63, lr = l & 15, lk = l >> 4;
    const int ch = w * 16 + lr;

    f32x4 az[2], ar[2], agc[2], ahc[2];
    #pragma unroll
    for (int rt = 0; rt < 2; ++rt)
        #pragma unroll
        for (int i = 0; i < 4; ++i) {
            int nl = rt * 16 + lk * 4 + i;
            const float* g = gxf0 + (size_t)(n0 + nl) * G3v;
            az[rt][i]  = g[ch];
            ar[rt][i]  = g[128 + ch];
            agc[rt][i] = g[256 + ch];
            ahc[rt][i] = 0.f;
        }
    #pragma unroll
    for (int kk = 0; kk < 4; ++kk) {
        const int kb = kk * 32 + lk * 8;
        bf16x8 bz = *(const bf16x8*)(Wht + (size_t)(ch) * HHv + kb);
        bf16x8 br = *(const bf16x8*)(Wht + (size_t)(128 + ch) * HHv + kb);
        bf16x8 bc = *(const bf16x8*)(Wht + (size_t)(256 + ch) * HHv + kb);
        #pragma unroll
        for (int rt = 0; rt < 2; ++rt) {
            bf16x8 a = *(const bf16x8*)&hs[rt * 16 + lr][kb];
            az[rt] = MFMA(a, bz, az[rt]);
            ar[rt] = MFMA(a, br, ar[rt]);
            ahc[rt] = MFMA(a, bc, ahc[rt]);
        }
    }
    #pragma unroll
    for (int rt = 0; rt < 2; ++rt)
        #pragma unroll
        for (int i = 0; i < 4; ++i) {
            int r2 = rt * 16 + lk * 4 + i;
            float z  = sigmoidf_(az[rt][i]);
            float rr = sigmoidf_(ar[rt][i]);
            float c  = tanhf(agc[rt][i] + rr * ahc[rt][i]);
            float hn = z * bf2f(hs[r2][ch]) + (1.f - z) * c;
            hnb[r2][ch] = f2bf(hn);
        }
    __syncthreads();
    {
        int chx = tid >> 2, g = tid & 3;
        ushort8 v;
        #pragma unroll
        for (int k = 0; k < 8; ++k) v[k] = hnb[g * 8 + k][chx];
        *(ushort8*)(xt + (size_t)(b * HHv + chx) * KPAD + n0 + g * 8) = v;
    }
}

// ---------------------------------------------------------------------------
// Fused step kernel. 32 nodes x 2 batches (64 rows), 512 threads = 8 waves.
// WHICH=0 (K_A): gconv0(h0[t]) -> d -> GRU1 -> h1[t]      (x-GEMM K=128 from m1s)
// WHICH=1 (K_B): gconv1(h1[t]) -> d -> proj out[t] -> GRU0 -> h0[t+1] (x K=32)
// XCD swizzle: each XCD owns a contiguous b-range (88 = 8 y-blocks x 11 x).
// ---------------------------------------------------------------------------
template<int WHICH>
__global__ __launch_bounds__(512) void fused_step(
    const ushort* __restrict__ xtB,
    const ushort* __restrict__ xtH,
    ushort* __restrict__ xtO,
    const ushort* __restrict__ Ab1,
    const ushort* __restrict__ Ab2,
    const ushort* __restrict__ W1t,
    const ushort* __restrict__ W2t,
    const ushort* __restrict__ Wxt,     // [384][KXP]
    const ushort* __restrict__ Wht,     // [384][128]
    const float* __restrict__ gxf,      // [352][384] fp32 (incl bias)
    const float* __restrict__ label,
    const float* __restrict__ Wp,
    const float* __restrict__ pfeat,    // [352][2]
    float* __restrict__ out,
    int t)
{
    constexpr int KXP = (WHICH == 0) ? 128 : 32;
    __shared__ ushort m1s[64][136];     // GEMM1 out / d (x-buffer for GRU)
    __shared__ ushort m2s[64][136];     // GEMM1 out / h-new
    __shared__ ushort hs[64][136];      // h-old
    __shared__ ushort xs[64][40];       // WHICH==1 x-data
    __shared__ float  os[64][2];

    // XCD-aware swizzle (bijective: 704 = 8 XCD x 88)
    int rid = blockIdx.x + GX * blockIdx.y;
    int xcd = rid & 7, rank = rid >> 3;
    int qy = rank / GX;
    const int n0 = (rank - qy * GX) * 32;
    const int b0 = (xcd * 8 + qy) * 2;

    const int tid = threadIdx.x;
    const int w = tid >> 6, l = tid & 63, lr = l & 15, lk = l >> 4;

    // ---- stage h-old (transpose from xtH): 256 cols x 32 nodes ----
    {
        int chg = tid >> 1, g = tid & 1;
        int bl = chg >> 7, ch = chg & 127;
        const ushort* src = xtH + (size_t)((b0 + bl) * HHv + ch) * KPAD + n0 + g * 16;
        ushort8 v0 = *(const ushort8*)src;
        ushort8 v1 = *(const ushort8*)(src + 8);
        #pragma unroll
        for (int k = 0; k < 8; ++k) hs[bl * 32 + g * 16 + k][ch] = v0[k];
        #pragma unroll
        for (int k = 0; k < 8; ++k) hs[bl * 32 + g * 16 + 8 + k][ch] = v1[k];
    }

    // ---- GEMM1: m = A*X, 32 n-rows x 256 cols, K=352 ----
    f32x4 m1[2][2], m2[2][2];
    #pragma unroll
    for (int rt = 0; rt < 2; ++rt)
        #pragma unroll
        for (int f = 0; f < 2; ++f) {
            m1[rt][f] = (f32x4){0.f,0.f,0.f,0.f};
            m2[rt][f] = (f32x4){0.f,0.f,0.f,0.f};
        }
    #pragma unroll 2
    for (int kk = 0; kk < KPAD / 32; ++kk) {
        const int kb = kk * 32 + lk * 8;
        bf16x8 a1[2], a2[2];
        #pragma unroll
        for (int rt = 0; rt < 2; ++rt) {
            a1[rt] = *(const bf16x8*)(Ab1 + (size_t)(n0 + rt * 16 + lr) * KPAD + kb);
            a2[rt] = *(const bf16x8*)(Ab2 + (size_t)(n0 + rt * 16 + lr) * KPAD + kb);
        }
        #pragma unroll
        for (int f = 0; f < 2; ++f) {
            bf16x8 bx = *(const bf16x8*)(xtB + (size_t)(b0 * HHv + w * 32 + f * 16 + lr) * KPAD + kb);
            #pragma unroll
            for (int rt = 0; rt < 2; ++rt) {
                m1[rt][f] = MFMA(a1[rt], bx, m1[rt][f]);
                m2[rt][f] = MFMA(a2[rt], bx, m2[rt][f]);
            }
        }
    }
    #pragma unroll
    for (int rt = 0; rt < 2; ++rt)
        #pragma unroll
        for (int f = 0; f < 2; ++f) {
            int colg = w * 32 + f * 16 + lr;
            int bl = colg >> 7, ch = colg & 127;
            #pragma unroll
            for (int i = 0; i < 4; ++i) {
                int r2 = bl * 32 + rt * 16 + lk * 4 + i;
                m1s[r2][ch] = f2bf(m1[rt][f][i]);
                m2s[r2][ch] = f2bf(m2[rt][f][i]);
            }
        }
    __syncthreads();

    // ---- GEMM2: d = 0.5*(m1@W1 + m2@W2), 64 rows x 128, K=128 ----
    f32x4 dacc[4];
    #pragma unroll
    for (int rt = 0; rt < 4; ++rt) dacc[rt] = (f32x4){0.f,0.f,0.f,0.f};
    #pragma unroll
    for (int kk = 0; kk < 4; ++kk) {
        const int kb = kk * 32 + lk * 8;
        bf16x8 b1 = *(const bf16x8*)(W1t + (size_t)(w * 16 + lr) * HHv + kb);
        bf16x8 b2 = *(const bf16x8*)(W2t + (size_t)(w * 16 + lr) * HHv + kb);
        #pragma unroll
        for (int rt = 0; rt < 4; ++rt) {
            bf16x8 a1x = *(const bf16x8*)&m1s[rt * 16 + lr][kb];
            bf16x8 a2x = *(const bf16x8*)&m2s[rt * 16 + lr][kb];
            dacc[rt] = MFMA(a1x, b1, dacc[rt]);
            dacc[rt] = MFMA(a2x, b2, dacc[rt]);
        }
    }
    __syncthreads();   // GEMM2 done reading m1s/m2s

    // ---- d -> m1s (x-buffer / projection input) ----
    {
        const int ch = w * 16 + lr;
        #pragma unroll
        for (int rt = 0; rt < 4; ++rt)
            #pragma unroll
            for (int i = 0; i < 4; ++i)
                m1s[rt * 16 + lk * 4 + i][ch] = f2bf(0.5f * dacc[rt][i]);
    }
    __syncthreads();

    if (WHICH == 1) {
        // ---- projection: out = d @ Wp_d + pfeat ----
        {
            int r2p = tid >> 3, sub = tid & 7;
            float a0 = 0.f, a1 = 0.f;
            #pragma unroll
            for (int q = 0; q < 16; ++q) {
                int k = sub * 16 + q;
                float v = bf2f(m1s[r2p][k]);
                a0 = fmaf(v, Wp[k * 2 + 0], a0);
                a1 = fmaf(v, Wp[k * 2 + 1], a1);
            }
            #pragma unroll
            for (int o = 4; o > 0; o >>= 1) {
                a0 += __shfl_down(a0, o, 8);
                a1 += __shfl_down(a1, o, 8);
            }
            if (sub == 0) {
                int n = n0 + (r2p & 31);
                os[r2p][0] = a0 + pfeat[n * 2 + 0];
                os[r2p][1] = a1 + pfeat[n * 2 + 1];
            }
        }
        __syncthreads();
        // write out[t] + build xs = [out(2) | aux(2) | 0...]
        if (tid < 128) {
            int r2 = tid >> 1, c = tid & 1;
            int n = n0 + (r2 & 31), b = b0 + (r2 >> 5);
            if (n < NN)
                out[(((size_t)n * BBv + b) * TTv + t) * ODDv + c] = os[r2][c];
        }
        for (int e = tid; e < 64 * 32; e += 512) {
            int r2 = e >> 5, k = e & 31;
            int n = n0 + (r2 & 31), b = b0 + (r2 >> 5);
            int nc = (n > NN - 1) ? NN - 1 : n;
            ushort v;
            if (k < 2)      v = f2bf(os[r2][k]);
            else if (k < 4) v = f2bf(label[(((size_t)nc * BBv + b) * TTv + t) * 4 + 2 + (k - 2)]);
            else            v = 0;
            xs[r2][k] = v;
        }
        __syncthreads();
    }

    // ---- GRU: g = x@Wx (C-init = gxf incl bias) + h@Wh ----
    const int ch = w * 16 + lr;
    f32x4 az[4], ar[4], agc[4], ahc[4];
    #pragma unroll
    for (int rt = 0; rt < 4; ++rt)
        #pragma unroll
        for (int i = 0; i < 4; ++i) {
            int nl = (rt * 16 + lk * 4 + i) & 31;
            const float* g = gxf + (size_t)(n0 + nl) * G3v;
            az[rt][i]  = g[ch];
            ar[rt][i]  = g[128 + ch];
            agc[rt][i] = g[256 + ch];
            ahc[rt][i] = 0.f;
        }
    #pragma unroll
    for (int kk = 0; kk < KXP / 32; ++kk) {
        const int kb = kk * 32 + lk * 8;
        bf16x8 bz = *(const bf16x8*)(Wxt + (size_t)ch * KXP + kb);
        bf16x8 br = *(const bf16x8*)(Wxt + (size_t)(128 + ch) * KXP + kb);
        bf16x8 bc = *(const bf16x8*)(Wxt + (size_t)(256 + ch) * KXP + kb);
        #pragma unroll
        for (int rt = 0; rt < 4; ++rt) {
            bf16x8 a = (WHICH == 0)
                ? *(const bf16x8*)&m1s[rt * 16 + lr][kb]
                : *(const bf16x8*)&xs[rt * 16 + lr][kb];
            az[rt] = MFMA(a, bz, az[rt]);
            ar[rt] = MFMA(a, br, ar[rt]);
            agc[rt] = MFMA(a, bc, agc[rt]);
        }
    }
    #pragma unroll
    for (int kk = 0; kk < 4; ++kk) {
        const int kb = kk * 32 + lk * 8;
        bf16x8 bz = *(const bf16x8*)(Wht + (size_t)ch * HHv + kb);
        bf16x8 br = *(const bf16x8*)(Wht + (size_t)(128 + ch) * HHv + kb);
        bf16x8 bc = *(const bf16x8*)(Wht + (size_t)(256 + ch) * HHv + kb);
        #pragma unroll
        for (int rt = 0; rt < 4; ++rt) {
            bf16x8 a = *(const bf16x8*)&hs[rt * 16 + lr][kb];
            az[rt] = MFMA(a, bz, az[rt]);
            ar[rt] = MFMA(a, br, ar[rt]);
            ahc[rt] = MFMA(a, bc, ahc[rt]);
        }
    }

    // ---- gating -> m2s ----
    #pragma unroll
    for (int rt = 0; rt < 4; ++rt)
        #pragma unroll
        for (int i = 0; i < 4; ++i) {
            int r2 = rt * 16 + lk * 4 + i;
            float z  = sigmoidf_(az[rt][i]);
            float rr = sigmoidf_(ar[rt][i]);
            float c  = tanhf(agc[rt][i] + rr * ahc[rt][i]);
            float hn = z * bf2f(hs[r2][ch]) + (1.f - z) * c;
            m2s[r2][ch] = f2bf(hn);
        }
    __syncthreads();

    // ---- write h-new transposed to xtO ----
    {
        int chg = tid >> 1, g = tid & 1;
        int bl = chg >> 7, chx = chg & 127;
        ushort8 v0, v1;
        #pragma unroll
        for (int k = 0; k < 8; ++k) v0[k] = m2s[bl * 32 + g * 16 + k][chx];
        #pragma unroll
        for (int k = 0; k < 8; ++k) v1[k] = m2s[bl * 32 + g * 16 + 8 + k][chx];
        ushort* dst = xtO + (size_t)((b0 + bl) * HHv + chx) * KPAD + n0 + g * 16;
        *(ushort8*)dst = v0;
        *(ushort8*)(dst + 8) = v1;
    }
}

// ---------------------------------------------------------------------------
extern "C" void kernel_launch(void* const* d_in, const int* in_sizes, int n_in,
                              void* d_out, int out_size, void* d_ws, size_t ws_size,
                              hipStream_t stream)
{
    const float* feature = (const float*)d_in[0];
    const float* label   = (const float*)d_in[1];
    const float* state0  = (const float*)d_in[2];
    const float* state1  = (const float*)d_in[3];
    const float* Wx0 = (const float*)d_in[4];
    const float* Wh0 = (const float*)d_in[5];
    const float* b0  = (const float*)d_in[6];
    const float* Wx1 = (const float*)d_in[7];
    const float* Wh1 = (const float*)d_in[8];
    const float* b1  = (const float*)d_in[9];
    const float* A01 = (const float*)d_in[10];
    const float* A02 = (const float*)d_in[11];
    const float* Wg01 = (const float*)d_in[12];
    const float* Wg02 = (const float*)d_in[13];
    const float* A11 = (const float*)d_in[14];
    const float* A12 = (const float*)d_in[15];
    const float* Wg11 = (const float*)d_in[16];
    const float* Wg12 = (const float*)d_in[17];
    const float* Wp  = (const float*)d_in[18];
    const float* bp  = (const float*)d_in[19];

    float* out = (float*)d_out;

    char* p = (char*)d_ws;
    auto alloc = [&](size_t bytes) {
        void* r = (void*)p; p += (bytes + 255) & ~(size_t)255; return r;
    };
    const size_t XTSZ = (size_t)BBv * HHv * KPAD;
    ushort* xt0[2] = { (ushort*)alloc(XTSZ * 2), (ushort*)alloc(XTSZ * 2) };
    ushort* xt1[2] = { (ushort*)alloc(XTSZ * 2), (ushort*)alloc(XTSZ * 2) };
    ushort* Ab01 = (ushort*)alloc((size_t)NPAD * KPAD * 2);
    ushort* Ab02 = (ushort*)alloc((size_t)NPAD * KPAD * 2);
    ushort* Ab11 = (ushort*)alloc((size_t)NPAD * KPAD * 2);
    ushort* Ab12 = (ushort*)alloc((size_t)NPAD * KPAD * 2);
    ushort* Wx0t = (ushort*)alloc((size_t)G3v * 32 * 2);
    ushort* Wh0t = (ushort*)alloc((size_t)G3v * HHv * 2);
    ushort* Wx1t = (ushort*)alloc((size_t)G3v * HHv * 2);
    ushort* Wh1t = (ushort*)alloc((size_t)G3v * HHv * 2);
    ushort* Wg01t = (ushort*)alloc((size_t)HHv * HHv * 2);
    ushort* Wg02t = (ushort*)alloc((size_t)HHv * HHv * 2);
    ushort* Wg11t = (ushort*)alloc((size_t)HHv * HHv * 2);
    ushort* Wg12t = (ushort*)alloc((size_t)HHv * HHv * 2);
    float*  gxf0 = (float*)alloc((size_t)NPAD * G3v * 4);
    float*  gxf1 = (float*)alloc((size_t)NPAD * G3v * 4);
    float*  pfe  = (float*)alloc((size_t)NPAD * 2 * 4);

    auto cdiv = [](int a, int b) { return (a + b - 1) / b; };
    wtrans_kernel<<<cdiv(G3v * 32, 256), 256, 0, stream>>>(Wx0, Wx0t, 4, G3v, 32);
    wtrans_kernel<<<cdiv(G3v * HHv, 256), 256, 0, stream>>>(Wh0, Wh0t, HHv, G3v, HHv);
    wtrans_kernel<<<cdiv(G3v * HHv, 256), 256, 0, stream>>>(Wx1, Wx1t, HHv, G3v, HHv);
    wtrans_kernel<<<cdiv(G3v * HHv, 256), 256, 0, stream>>>(Wh1, Wh1t, HHv, G3v, HHv);
    wtrans_kernel<<<cdiv(HHv * HHv, 256), 256, 0, stream>>>(Wg01, Wg01t, HHv, HHv, HHv);
    wtrans_kernel<<<cdiv(HHv * HHv, 256), 256, 0, stream>>>(Wg02, Wg02t, HHv, HHv, HHv);
    wtrans_kernel<<<cdiv(HHv * HHv, 256), 256, 0, stream>>>(Wg11, Wg11t, HHv, HHv, HHv);
    wtrans_kernel<<<cdiv(HHv * HHv, 256), 256, 0, stream>>>(Wg12, Wg12t, HHv, HHv, HHv);
    aconv_kernel<<<cdiv(NPAD * KPAD, 256), 256, 0, stream>>>(A01, Ab01);
    aconv_kernel<<<cdiv(NPAD * KPAD, 256), 256, 0, stream>>>(A02, Ab02);
    aconv_kernel<<<cdiv(NPAD * KPAD, 256), 256, 0, stream>>>(A11, Ab11);
    aconv_kernel<<<cdiv(NPAD * KPAD, 256), 256, 0, stream>>>(A12, Ab12);
    gxf_kernel<<<NPAD, G3v, 0, stream>>>(Wx0, b0, feature, gxf0, 4);
    gxf_kernel<<<NPAD, G3v, 0, stream>>>(Wx1, b1, feature, gxf1, 128);
    pfeat_kernel<<<NPAD, 64, 0, stream>>>(Wp, bp, feature, pfe);
    strans_kernel<<<cdiv((int)XTSZ, 256), 256, 0, stream>>>(state1, xt1[0]);

    // prologue: h0[0] = GRU0(data=0, state0) -> xt0[0]
    gru0_init<<<dim3(GX, BBv), 512, 0, stream>>>(state0, gxf0, Wh0t, xt0[0]);

    const dim3 grid(GX, GY);
    for (int t = 0; t < TTv; ++t) {
        // K_A: gconv0(h0[t]) + GRU1 -> h1[t]
        fused_step<0><<<grid, 512, 0, stream>>>(
            xt0[t & 1], xt1[t & 1], xt1[(t + 1) & 1],
            Ab01, Ab02, Wg01t, Wg02t, Wx1t, Wh1t, gxf1,
            nullptr, nullptr, nullptr, nullptr, t);
        // K_B: gconv1(h1[t]) + proj(out[t]) + GRU0 -> h0[t+1]
        fused_step<1><<<grid, 512, 0, stream>>>(
            xt1[(t + 1) & 1], xt0[t & 1], xt0[(t + 1) & 1],
            Ab11, Ab12, Wg11t, Wg12t, Wx0t, Wh0t, gxf0,
            label, Wp, pfe, out, t);
    }
}